// Round 13
// baseline (155.816 us; speedup 1.0000x reference)
//
#include <hip/hip_runtime.h>
#include <hip/hip_bf16.h>
#include <math.h>

#define BATCH 2
#define SEQ   2048
#define HID   1024
#define NHEAD 16
#define ROWS  (BATCH*SEQ)   // 4096
#define QK_N  2048          // Q|K buffer row stride
#define VT_N  (BATCH*SEQ)   // V^T buffer row stride (4096)

// Q pre-scaled by 1/sqrt(64) * log2(e): attention works in exp2 domain.
#define Q_SCALE 0.18033688011112042f

typedef __attribute__((ext_vector_type(8))) short bf16x8;   // 8 bf16 in 4 VGPRs
typedef __attribute__((ext_vector_type(4))) float f32x4;

__device__ __forceinline__ unsigned short f2b(float f) {
    unsigned u = __float_as_uint(f);
    u += 0x7FFF + ((u >> 16) & 1);          // round-to-nearest-even
    return (unsigned short)(u >> 16);
}
// pack two f32 -> u32 of 2 bf16 (lo=a, hi=b) via compiler (emits v_cvt_pk_bf16_f32)
__device__ __forceinline__ unsigned pk2c(float a, float b) {
    __hip_bfloat162 h = __float22bfloat162_rn(float2{a, b});
    union { __hip_bfloat162 h2; unsigned u; } cv; cv.h2 = h;
    return cv.u;
}

// global -> LDS direct copy, 16B per lane; LDS dest is wave-uniform base + lane*16
#define GLOAD_LDS16(gp, lp) \
    __builtin_amdgcn_global_load_lds((const __attribute__((address_space(1))) void*)(gp), \
                                     (__attribute__((address_space(3))) void*)(lp), 16, 0, 0)

// fused f32->bf16 conversion for the three input tensors
__global__ __launch_bounds__(256)
void cvt_all(const float* __restrict__ a, unsigned short* __restrict__ oa, int na4,
             const float* __restrict__ b, unsigned short* __restrict__ ob, int nb4,
             const float* __restrict__ c, unsigned short* __restrict__ oc, int nc4) {
    int i = blockIdx.x * 256 + threadIdx.x;
    const float* src; unsigned short* dst; int j;
    if (i < na4)            { src = a; dst = oa; j = i; }
    else if (i < na4 + nb4) { src = b; dst = ob; j = i - na4; }
    else if (i < na4 + nb4 + nc4) { src = c; dst = oc; j = i - na4 - nb4; }
    else return;
    float4 v = reinterpret_cast<const float4*>(src)[j];
    ushort4 o;
    o.x = f2b(v.x); o.y = f2b(v.y); o.z = f2b(v.z); o.w = f2b(v.w);
    reinterpret_cast<ushort4*>(dst)[j] = o;
}

// ================= shared BK=64 GEMM core (128x128 tile) ======================
// LDS rows are 128B (64 bf16), XOR-swizzled with (row&7): source granule
// (l&7)^(l>>3), linear gload_lds dest, read offset ((ks*4+l4)^(row&7))<<4.
// Identical scheme to the attn kernel's verified K/V staging (0-conflict).
#define GEMM_CORE(A_, B_, Kdim)                                                          \
    f32x4 acc[4][4];                                                                     \
    _Pragma("unroll")                                                                    \
    for (int m = 0; m < 4; ++m)                                                          \
        _Pragma("unroll")                                                                \
        for (int n = 0; n < 4; ++n) acc[m][n] = (f32x4)0.0f;                             \
    const int sr8  = l >> 3;                                                             \
    const int slot = (l & 7) ^ sr8;                                                      \
    for (int k0 = 0; k0 < (Kdim); k0 += 64) {                                            \
        __syncthreads();                                                                 \
        _Pragma("unroll")                                                                \
        for (int c = 0; c < 4; ++c) {                                                    \
            int r = w * 32 + c * 8 + sr8;                                                \
            GLOAD_LDS16((A_) + (row0 + r) * (Kdim) + k0 + slot * 8,                      \
                        As + (w * 32 + c * 8) * 64);                                     \
            GLOAD_LDS16((B_) + (col0 + r) * (Kdim) + k0 + slot * 8,                      \
                        Bs + (w * 32 + c * 8) * 64);                                     \
        }                                                                                \
        __syncthreads();                                                                 \
        _Pragma("unroll")                                                                \
        for (int ks = 0; ks < 2; ++ks) {                                                 \
            bf16x8 af[4], bfr[4];                                                        \
            _Pragma("unroll")                                                            \
            for (int m = 0; m < 4; ++m) {                                                \
                int row = wm * 64 + m * 16 + l15;                                        \
                af[m] = *(const bf16x8*)((const char*)As + row * 128 +                   \
                                         (((ks * 4 + l4) ^ (row & 7)) << 4));            \
            }                                                                            \
            _Pragma("unroll")                                                            \
            for (int n = 0; n < 4; ++n) {                                                \
                int row = wn * 64 + n * 16 + l15;                                        \
                bfr[n] = *(const bf16x8*)((const char*)Bs + row * 128 +                  \
                                          (((ks * 4 + l4) ^ (row & 7)) << 4));           \
            }                                                                            \
            _Pragma("unroll")                                                            \
            for (int m = 0; m < 4; ++m)                                                  \
                _Pragma("unroll")                                                        \
                for (int n = 0; n < 4; ++n)                                              \
                    acc[m][n] = __builtin_amdgcn_mfma_f32_16x16x32_bf16(af[m], bfr[n],   \
                                                                        acc[m][n], 0, 0, 0); \
        }                                                                                \
    }

// ---- fused QK + V^T projection, one dispatch ---------------------------------
// blocks 0..511:   QK: C[s][c] = X[s]·Wqk[c] + b[c], c<1024 scaled; stride QK_N
// blocks 512..767: VT: D[hd][s] = Wv[hd]·X[s] + b[2048+hd]; stride VT_N (coalesced)
__global__ __launch_bounds__(256)
void proj_fused(const unsigned short* __restrict__ fbf,
                const unsigned short* __restrict__ wbf,
                const float* __restrict__ qkv_b,
                unsigned short* __restrict__ qkbf,
                unsigned short* __restrict__ vtD) {
    __shared__ __align__(16) unsigned short As[128 * 64];   // 16 KB, 128B rows
    __shared__ __align__(16) unsigned short Bs[128 * 64];   // 16 KB
    const int tid = threadIdx.x;
    const int w = tid >> 6, l = tid & 63;
    const int wm = w >> 1, wn = w & 1;
    const int l15 = l & 15, l4 = l >> 4;

    const int bx = blockIdx.x;
    const bool isQK = bx < 512;
    const unsigned short* A;
    const unsigned short* Bm;
    long row0, col0;
    if (isQK) {
        row0 = (long)(bx >> 4) * 128;        // 32 row tiles over 4096 seq rows
        col0 = (long)(bx & 15) * 128;        // 16 col tiles over 2048 qk cols
        A = fbf;  Bm = wbf;
    } else {
        int r = bx - 512;
        row0 = (long)(r >> 5) * 128;         // 8 row tiles over 1024 hd rows
        col0 = (long)(r & 31) * 128;         // 32 col tiles over 4096 seq cols
        A = wbf + (size_t)2048 * 1024;       // W_v
        Bm = fbf;
    }

    GEMM_CORE(A, Bm, HID)

    #pragma unroll
    for (int m = 0; m < 4; ++m) {
        #pragma unroll
        for (int n = 0; n < 4; ++n) {
            long ccol = col0 + wn * 64 + n * 16 + l15;
            #pragma unroll
            for (int r2 = 0; r2 < 4; ++r2) {
                long crow = row0 + wm * 64 + m * 16 + l4 * 4 + r2;
                if (isQK) {
                    float v = acc[m][n][r2] + qkv_b[ccol];
                    qkbf[crow * QK_N + ccol] = (ccol < 1024) ? f2b(v * Q_SCALE) : f2b(v);
                } else {
                    float v = acc[m][n][r2] + qkv_b[2048 + crow];
                    vtD[crow * VT_N + ccol] = f2b(v);
                }
            }
        }
    }
}

// ---- C[M,N] = A[M,K] * B[N,K]^T + bias(col), f32 out (out-projection) --------
__global__ __launch_bounds__(256)
void gemm_out(const unsigned short* __restrict__ A, const unsigned short* __restrict__ B,
              const float* __restrict__ bias, float* __restrict__ Cout,
              int M, int N, int K) {
    __shared__ __align__(16) unsigned short As[128 * 64];
    __shared__ __align__(16) unsigned short Bs[128 * 64];
    const int tid = threadIdx.x;
    const int w = tid >> 6, l = tid & 63;
    const int wm = w >> 1, wn = w & 1;
    const int l15 = l & 15, l4 = l >> 4;
    const long row0 = (long)blockIdx.y * 128;
    const long col0 = (long)blockIdx.x * 128;

    GEMM_CORE(A, B, K)

    #pragma unroll
    for (int m = 0; m < 4; ++m) {
        #pragma unroll
        for (int n = 0; n < 4; ++n) {
            long ccol = col0 + wn * 64 + n * 16 + l15;
            float bv = bias[ccol];
            #pragma unroll
            for (int r2 = 0; r2 < 4; ++r2) {
                long crow = row0 + wm * 64 + m * 16 + l4 * 4 + r2;
                Cout[crow * N + ccol] = acc[m][n][r2] + bv;
            }
        }
    }
}

// ---- flash attention, bf16 MFMA, k-split wave specialization -----------------
// (unchanged from R11 — control)
__global__ __launch_bounds__(256, 4)
void attn_mfma(const unsigned short* __restrict__ qk, const unsigned short* __restrict__ vtD,
               unsigned short* __restrict__ attno, const int* __restrict__ use_mask) {
    __shared__ __align__(16) unsigned short Ks [64 * 64];   // [token][d], swz(row&7)
    __shared__ __align__(16) unsigned short Vts[64 * 64];   // [d][token], swz(row&7)
    __shared__ __align__(16) unsigned short Ps [4][32 * 40];// per-wave P, 80B rows (bank-spread)
    const int tid = threadIdx.x;
    const int w = tid >> 6, l = tid & 63;
    const int l15 = l & 15, l4 = l >> 4;
    // XCD swizzle: 1024 blocks = 8 XCDs x 128; each XCD owns 4 consecutive bh
    const int bid  = blockIdx.x;
    const int orig = (bid & 7) * 128 + (bid >> 3);
    const int qt = orig & 31, bh = orig >> 5;
    const int b = bh >> 4, h = bh & 15;
    const int q0 = qt * 64;                   // block q-range [q0, q0+64)
    const int qh = w & 1, kh = w >> 1;        // wave's q-half / k-half
    const int wq0 = q0 + qh * 32;             // wave q-range [wq0, wq0+32)
    const int causal = use_mask[0];
    const int NT = causal ? (qt + 1) : (SEQ / 64);

    // Q fragments (B-op of swapped QK^T): col q = wq0 + m*16 + l15, d-slice ks*32+l4*8
    bf16x8 qf[2][2];
    #pragma unroll
    for (int m = 0; m < 2; ++m) {
        const unsigned short* qp = qk + (size_t)(b * SEQ + wq0 + m * 16 + l15) * QK_N + h * 64;
        qf[m][0] = *(const bf16x8*)(qp + l4 * 8);
        qf[m][1] = *(const bf16x8*)(qp + 32 + l4 * 8);
    }

    f32x4 o_acc[2][4];
    #pragma unroll
    for (int m = 0; m < 2; ++m)
        #pragma unroll
        for (int n = 0; n < 4; ++n) o_acc[m][n] = (f32x4)0.0f;
    f32x4 l_acc[2] = {(f32x4)0.0f, (f32x4)0.0f};   // partial row sums (ones-MFMA)

    bf16x8 ones;
    #pragma unroll
    for (int j = 0; j < 8; ++j) ones[j] = (short)0x3F80;

    const int srow = l >> 3, g = l & 7;
    const int r0   = w * 16 + srow;           // rows staged by this thread (and +8)
    const int wso  = (g ^ srow) << 3;         // swizzled granule offset (ushorts)
    unsigned short* pw = Ps[w];

    // walking source pointers (hoisted 64-bit address math)
    const unsigned short* kp = qk + (size_t)b * SEQ * QK_N + 1024 + h * 64
                                  + (size_t)r0 * QK_N + g * 8;
    const unsigned short* vp = vtD + (size_t)(h * 64 + r0) * VT_N + b * SEQ + g * 8;

    // prologue: prefetch tile 0 into registers (T14)
    bf16x8 kreg[2], vreg[2];
    kreg[0] = *(const bf16x8*)(kp);
    kreg[1] = *(const bf16x8*)(kp + 8 * QK_N);
    vreg[0] = *(const bf16x8*)(vp);
    vreg[1] = *(const bf16x8*)(vp + 8 * VT_N);
    kp += (size_t)64 * QK_N;
    vp += 64;

    for (int kt = 0; kt < NT; ++kt) {
        __syncthreads();   // previous tile's LDS reads done
        #pragma unroll
        for (int c = 0; c < 2; ++c) {
            *(bf16x8*)(Ks  + (r0 + c * 8) * 64 + wso) = kreg[c];
            *(bf16x8*)(Vts + (r0 + c * 8) * 64 + wso) = vreg[c];
        }
        __syncthreads();   // tile staged

        // issue next tile's global loads; latency hides under compute below
        if (kt + 1 < NT) {
            kreg[0] = *(const bf16x8*)(kp);
            kreg[1] = *(const bf16x8*)(kp + 8 * QK_N);
            vreg[0] = *(const bf16x8*)(vp);
            vreg[1] = *(const bf16x8*)(vp + 8 * VT_N);
            kp += (size_t)64 * QK_N;
            vp += 64;
        }

        // S^T = K Q^T over the wave's 32x32 patch:
        // s_acc[n2][m]: k-row = kt*64 + kh*32 + n2*16 + l4*4 + r2, q-col = wq0 + m*16 + l15
        f32x4 s_acc[2][2];
        #pragma unroll
        for (int n2 = 0; n2 < 2; ++n2)
            #pragma unroll
            for (int m = 0; m < 2; ++m) s_acc[n2][m] = (f32x4)0.0f;
        __builtin_amdgcn_s_setprio(1);
        #pragma unroll
        for (int ks = 0; ks < 2; ++ks) {
            #pragma unroll
            for (int n2 = 0; n2 < 2; ++n2) {
                int row = kh * 32 + n2 * 16 + l15;
                bf16x8 kf = *(const bf16x8*)((const char*)Ks + row * 128 + (((ks * 4 + l4) ^ (row & 7)) << 4));
                #pragma unroll
                for (int m = 0; m < 2; ++m)
                    s_acc[n2][m] = __builtin_amdgcn_mfma_f32_16x16x32_bf16(kf, qf[m][ks], s_acc[n2][m], 0, 0, 0);
            }
        }
        __builtin_amdgcn_s_setprio(0);

        if (causal) {
            int kk0 = kt * 64 + kh * 32;
            #pragma unroll
            for (int n2 = 0; n2 < 2; ++n2)
                #pragma unroll
                for (int m = 0; m < 2; ++m)
                    #pragma unroll
                    for (int r2 = 0; r2 < 4; ++r2) {
                        int krow = kk0 + n2 * 16 + l4 * 4 + r2;
                        int qcol = wq0 + m * 16 + l15;
                        if (krow > qcol) s_acc[n2][m][r2] = -INFINITY;
                    }
        }

        // P = exp2(S) raw; pack pairs (compiler cvt_pk); write b64 into 80B-stride
        // P rows (bank-spread: base bank cycles (prow*20)%32, 2-way max = free)
        #pragma unroll
        for (int m = 0; m < 2; ++m) {
            int prow = m * 16 + l15;
            #pragma unroll
            for (int n2 = 0; n2 < 2; ++n2) {
                float p0 = exp2f(s_acc[n2][m][0]);
                float p1 = exp2f(s_acc[n2][m][1]);
                float p2 = exp2f(s_acc[n2][m][2]);
                float p3 = exp2f(s_acc[n2][m][3]);
                uint2 pk;
                pk.x = pk2c(p0, p1);
                pk.y = pk2c(p2, p3);
                *(uint2*)((char*)pw + prow * 80 + n2 * 32 + l4 * 8) = pk;
            }
        }

        // O += P V over the wave's k-half (single K=32 chunk); l via ones-MFMA
        __builtin_amdgcn_s_setprio(1);
        bf16x8 pf[2];
        #pragma unroll
        for (int m = 0; m < 2; ++m) {
            int prow = m * 16 + l15;
            pf[m] = *(const bf16x8*)((const char*)pw + prow * 80 + l4 * 16);
            l_acc[m] = __builtin_amdgcn_mfma_f32_16x16x32_bf16(pf[m], ones, l_acc[m], 0, 0, 0);
        }
        #pragma unroll
        for (int n = 0; n < 4; ++n) {
            int vrow = n * 16 + l15;
            bf16x8 vf = *(const bf16x8*)((const char*)Vts + vrow * 128 + (((kh * 4 + l4) ^ (vrow & 7)) << 4));
            #pragma unroll
            for (int m = 0; m < 2; ++m)
                o_acc[m][n] = __builtin_amdgcn_mfma_f32_16x16x32_bf16(pf[m], vf, o_acc[m][n], 0, 0, 0);
        }
        __builtin_amdgcn_s_setprio(0);
    }

    // ---- cross-wave merge: (qh, kh=0) += (qh, kh=1); normalize; write --------
    __syncthreads();                           // all tiles' LDS reads done
    float* mq = (float*)(qh ? Vts : Ks);       // 32q x 64d f32 = 8KB per q-half
    float* lb = (float*)&Ps[0][0];             // 64 f32 row sums
    if (kh == 1) {
        #pragma unroll
        for (int m = 0; m < 2; ++m) {
            #pragma unroll
            for (int r2 = 0; r2 < 4; ++r2) {
                int qr = m * 16 + l4 * 4 + r2;
                #pragma unroll
                for (int n = 0; n < 4; ++n)
                    mq[qr * 64 + n * 16 + l15] = o_acc[m][n][r2];
                if (l15 == 0) lb[qh * 32 + qr] = l_acc[m][r2];
            }
        }
    }
    __syncthreads();
    if (kh == 0) {
        #pragma unroll
        for (int m = 0; m < 2; ++m) {
            #pragma unroll
            for (int r2 = 0; r2 < 4; ++r2) {
                int qr = m * 16 + l4 * 4 + r2;
                float lt = l_acc[m][r2] + lb[qh * 32 + qr];
                float inv = 1.0f / lt;
                size_t orow = (size_t)(b * SEQ + wq0 + qr);
                #pragma unroll
                for (int n = 0; n < 4; ++n) {
                    float o = o_acc[m][n][r2] + mq[qr * 64 + n * 16 + l15];
                    attno[orow * HID + h * 64 + n * 16 + l15] = f2b(o * inv);
                }
            }
        }
    }
}

extern "C" void kernel_launch(void* const* d_in, const int* in_sizes, int n_in,
                              void* d_out, int out_size, void* d_ws, size_t ws_size,
                              hipStream_t stream) {
    const float* features = (const float*)d_in[0];
    const float* qkv_w    = (const float*)d_in[1];
    const float* qkv_b    = (const float*)d_in[2];
    const float* out_w    = (const float*)d_in[3];
    const float* out_b    = (const float*)d_in[4];
    const int*   use_mask = (const int*)d_in[5];

    char* ws = (char*)d_ws;
    unsigned short* fbf     = (unsigned short*)(ws);              // 8 MB  features bf16
    unsigned short* wbf     = (unsigned short*)(ws + 8388608);    // 6 MB  qkv_w bf16
    unsigned short* owbf    = (unsigned short*)(ws + 14680064);   // 2 MB  out_w bf16
    unsigned short* qkbf    = (unsigned short*)(ws + 16777216);   // 16 MB Q|K bf16 [4096][2048]
    unsigned short* vtD     = (unsigned short*)(ws + 33554432);   // 8 MB  V^T bf16 [1024][4096]
    unsigned short* attnobf = (unsigned short*)(ws + 41943040);   // 8 MB  attn out bf16

    cvt_all<<<8192, 256, 0, stream>>>(features, fbf, 1048576,
                                      qkv_w, wbf, 786432,
                                      out_w, owbf, 262144);

    // fused QK + V^T projection (768 blocks, one dispatch)
    proj_fused<<<768, 256, 0, stream>>>(fbf, wbf, qkv_b, qkbf, vtD);

    attn_mfma<<<1024, 256, 0, stream>>>(qkbf, vtD, attnobf, use_mask);

    // output projection: [4096,1024] @ [1024,1024]^T + b
    dim3 g3(HID / 128, ROWS / 128);     // (8, 32)
    gemm_out<<<g3, 256, 0, stream>>>(attnobf, owbf, out_b, (float*)d_out,
                                     ROWS, HID, HID);
}

// Round 14
// 141.495 us; speedup vs baseline: 1.1012x; 1.1012x over previous
//
#include <hip/hip_runtime.h>
#include <hip/hip_bf16.h>
#include <math.h>

#define BATCH 2
#define SEQ   2048
#define HID   1024
#define NHEAD 16
#define ROWS  (BATCH*SEQ)   // 4096
#define QK_N  2048          // Q|K buffer row stride
#define VT_N  (BATCH*SEQ)   // V^T buffer row stride (4096)

// Q pre-scaled by 1/sqrt(64) * log2(e): attention works in exp2 domain.
#define Q_SCALE 0.18033688011112042f

typedef __attribute__((ext_vector_type(8))) short bf16x8;   // 8 bf16 in 4 VGPRs
typedef __attribute__((ext_vector_type(4))) float f32x4;

__device__ __forceinline__ unsigned short f2b(float f) {
    unsigned u = __float_as_uint(f);
    u += 0x7FFF + ((u >> 16) & 1);          // round-to-nearest-even
    return (unsigned short)(u >> 16);
}
// pack two f32 -> u32 of 2 bf16 (lo=a, hi=b) via compiler (emits v_cvt_pk_bf16_f32)
__device__ __forceinline__ unsigned pk2c(float a, float b) {
    __hip_bfloat162 h = __float22bfloat162_rn(float2{a, b});
    union { __hip_bfloat162 h2; unsigned u; } cv; cv.h2 = h;
    return cv.u;
}

// global -> LDS direct copy, 16B per lane; LDS dest is wave-uniform base + lane*16
#define GLOAD_LDS16(gp, lp) \
    __builtin_amdgcn_global_load_lds((const __attribute__((address_space(1))) void*)(gp), \
                                     (__attribute__((address_space(3))) void*)(lp), 16, 0, 0)

// fused f32->bf16 conversion for the three input tensors
__global__ __launch_bounds__(256)
void cvt_all(const float* __restrict__ a, unsigned short* __restrict__ oa, int na4,
             const float* __restrict__ b, unsigned short* __restrict__ ob, int nb4,
             const float* __restrict__ c, unsigned short* __restrict__ oc, int nc4) {
    int i = blockIdx.x * 256 + threadIdx.x;
    const float* src; unsigned short* dst; int j;
    if (i < na4)            { src = a; dst = oa; j = i; }
    else if (i < na4 + nb4) { src = b; dst = ob; j = i - na4; }
    else if (i < na4 + nb4 + nc4) { src = c; dst = oc; j = i - na4 - nb4; }
    else return;
    float4 v = reinterpret_cast<const float4*>(src)[j];
    ushort4 o;
    o.x = f2b(v.x); o.y = f2b(v.y); o.z = f2b(v.z); o.w = f2b(v.w);
    reinterpret_cast<ushort4*>(dst)[j] = o;
}

// ---- fused QK + V^T projection, one dispatch (BK=32, reverted to R11 form) ---
// blocks 0..511:   QK: C[s][c] = X[s]·Wqk[c] + b[c], c<1024 scaled; stride QK_N
// blocks 512..767: VT: D[hd][s] = Wv[hd]·X[s] + b[2048+hd]; stride VT_N (coalesced)
__global__ __launch_bounds__(256)
void proj_fused(const unsigned short* __restrict__ fbf,
                const unsigned short* __restrict__ wbf,
                const float* __restrict__ qkv_b,
                unsigned short* __restrict__ qkbf,
                unsigned short* __restrict__ vtD) {
    __shared__ __align__(16) unsigned short As[128 * 32];   // 64B rows, swz(row&3)
    __shared__ __align__(16) unsigned short Bs[128 * 32];
    const int tid = threadIdx.x;
    const int w = tid >> 6, l = tid & 63;
    const int wm = w >> 1, wn = w & 1;
    const int l15 = l & 15, l4 = l >> 4;

    const int bx = blockIdx.x;
    const bool isQK = bx < 512;
    const unsigned short* A;
    const unsigned short* Bm;
    long row0, col0;
    if (isQK) {
        row0 = (long)(bx >> 4) * 128;        // 32 row tiles over 4096 seq rows
        col0 = (long)(bx & 15) * 128;        // 16 col tiles over 2048 qk cols
        A = fbf;  Bm = wbf;
    } else {
        int r = bx - 512;
        row0 = (long)(r >> 5) * 128;         // 8 row tiles over 1024 hd rows
        col0 = (long)(r & 31) * 128;         // 32 col tiles over 4096 seq cols
        A = wbf + (size_t)2048 * 1024;       // W_v
        Bm = fbf;
    }

    f32x4 acc[4][4];
    #pragma unroll
    for (int m = 0; m < 4; ++m)
        #pragma unroll
        for (int n = 0; n < 4; ++n) acc[m][n] = (f32x4)0.0f;

    const int lr   = l >> 2;                 // staging row within 16
    const int slot = (l & 3) ^ (lr & 3);     // pre-swizzled source granule

    for (int k0 = 0; k0 < HID; k0 += 32) {
        __syncthreads();
        #pragma unroll
        for (int c = 0; c < 2; ++c) {
            int r = w * 32 + c * 16 + lr;
            GLOAD_LDS16(A  + (row0 + r) * HID + k0 + slot * 8, As + (w * 32 + c * 16) * 32);
            GLOAD_LDS16(Bm + (col0 + r) * HID + k0 + slot * 8, Bs + (w * 32 + c * 16) * 32);
        }
        __syncthreads();

        bf16x8 af[4], bfr[4];
        #pragma unroll
        for (int m = 0; m < 4; ++m) {
            int row = wm * 64 + m * 16 + l15;
            af[m] = *(const bf16x8*)((const char*)As + row * 64 + ((l4 ^ (row & 3)) << 4));
        }
        #pragma unroll
        for (int n = 0; n < 4; ++n) {
            int row = wn * 64 + n * 16 + l15;
            bfr[n] = *(const bf16x8*)((const char*)Bs + row * 64 + ((l4 ^ (row & 3)) << 4));
        }
        #pragma unroll
        for (int m = 0; m < 4; ++m)
            #pragma unroll
            for (int n = 0; n < 4; ++n)
                acc[m][n] = __builtin_amdgcn_mfma_f32_16x16x32_bf16(af[m], bfr[n], acc[m][n], 0, 0, 0);
    }

    #pragma unroll
    for (int m = 0; m < 4; ++m) {
        #pragma unroll
        for (int n = 0; n < 4; ++n) {
            long ccol = col0 + wn * 64 + n * 16 + l15;
            #pragma unroll
            for (int r2 = 0; r2 < 4; ++r2) {
                long crow = row0 + wm * 64 + m * 16 + l4 * 4 + r2;
                if (isQK) {
                    float v = acc[m][n][r2] + qkv_b[ccol];
                    qkbf[crow * QK_N + ccol] = (ccol < 1024) ? f2b(v * Q_SCALE) : f2b(v);
                } else {
                    float v = acc[m][n][r2] + qkv_b[2048 + crow];
                    vtD[crow * VT_N + ccol] = f2b(v);
                }
            }
        }
    }
}

// ---- out-projection: C[M,N] = A[M,K]*B[N,K]^T + bias, 128x64 tile (2 blk/CU) -
__global__ __launch_bounds__(256)
void gemm_out(const unsigned short* __restrict__ A, const unsigned short* __restrict__ B,
              const float* __restrict__ bias, float* __restrict__ Cout,
              int M, int N, int K) {
    __shared__ __align__(16) unsigned short As[128 * 32];   // 8 KB
    __shared__ __align__(16) unsigned short Bs[64 * 32];    // 4 KB
    const int tid = threadIdx.x;
    const int w = tid >> 6, l = tid & 63;
    const int wm = w >> 1, wn = w & 1;       // wave owns 64 rows x 32 cols
    const int l15 = l & 15, l4 = l >> 4;
    const long row0 = (long)blockIdx.y * 128;
    const long col0 = (long)blockIdx.x * 64;

    f32x4 acc[4][2];
    #pragma unroll
    for (int m = 0; m < 4; ++m)
        #pragma unroll
        for (int n = 0; n < 2; ++n) acc[m][n] = (f32x4)0.0f;

    const int lr   = l >> 2;
    const int slot = (l & 3) ^ (lr & 3);

    for (int k0 = 0; k0 < K; k0 += 32) {
        __syncthreads();
        #pragma unroll
        for (int c = 0; c < 2; ++c) {
            int r = w * 32 + c * 16 + lr;
            GLOAD_LDS16(A + (row0 + r) * K + k0 + slot * 8, As + (w * 32 + c * 16) * 32);
        }
        {   // B tile: 64 rows, one load per thread
            int r = w * 16 + lr;
            GLOAD_LDS16(B + (col0 + r) * K + k0 + slot * 8, Bs + (w * 16) * 32);
        }
        __syncthreads();

        bf16x8 af[4], bfr[2];
        #pragma unroll
        for (int m = 0; m < 4; ++m) {
            int row = wm * 64 + m * 16 + l15;
            af[m] = *(const bf16x8*)((const char*)As + row * 64 + ((l4 ^ (row & 3)) << 4));
        }
        #pragma unroll
        for (int n = 0; n < 2; ++n) {
            int row = wn * 32 + n * 16 + l15;
            bfr[n] = *(const bf16x8*)((const char*)Bs + row * 64 + ((l4 ^ (row & 3)) << 4));
        }
        #pragma unroll
        for (int m = 0; m < 4; ++m)
            #pragma unroll
            for (int n = 0; n < 2; ++n)
                acc[m][n] = __builtin_amdgcn_mfma_f32_16x16x32_bf16(af[m], bfr[n], acc[m][n], 0, 0, 0);
    }

    #pragma unroll
    for (int m = 0; m < 4; ++m) {
        #pragma unroll
        for (int n = 0; n < 2; ++n) {
            long ccol = col0 + wn * 32 + n * 16 + l15;
            float bv = bias[ccol];
            #pragma unroll
            for (int r2 = 0; r2 < 4; ++r2) {
                long crow = row0 + wm * 64 + m * 16 + l4 * 4 + r2;
                Cout[crow * N + ccol] = acc[m][n][r2] + bv;
            }
        }
    }
}

// ---- flash attention, bf16 MFMA, k-split wave specialization -----------------
// (unchanged — control)
__global__ __launch_bounds__(256, 4)
void attn_mfma(const unsigned short* __restrict__ qk, const unsigned short* __restrict__ vtD,
               unsigned short* __restrict__ attno, const int* __restrict__ use_mask) {
    __shared__ __align__(16) unsigned short Ks [64 * 64];   // [token][d], swz(row&7)
    __shared__ __align__(16) unsigned short Vts[64 * 64];   // [d][token], swz(row&7)
    __shared__ __align__(16) unsigned short Ps [4][32 * 40];// per-wave P, 80B rows (bank-spread)
    const int tid = threadIdx.x;
    const int w = tid >> 6, l = tid & 63;
    const int l15 = l & 15, l4 = l >> 4;
    // XCD swizzle: 1024 blocks = 8 XCDs x 128; each XCD owns 4 consecutive bh
    const int bid  = blockIdx.x;
    const int orig = (bid & 7) * 128 + (bid >> 3);
    const int qt = orig & 31, bh = orig >> 5;
    const int b = bh >> 4, h = bh & 15;
    const int q0 = qt * 64;                   // block q-range [q0, q0+64)
    const int qh = w & 1, kh = w >> 1;        // wave's q-half / k-half
    const int wq0 = q0 + qh * 32;             // wave q-range [wq0, wq0+32)
    const int causal = use_mask[0];
    const int NT = causal ? (qt + 1) : (SEQ / 64);

    // Q fragments (B-op of swapped QK^T): col q = wq0 + m*16 + l15, d-slice ks*32+l4*8
    bf16x8 qf[2][2];
    #pragma unroll
    for (int m = 0; m < 2; ++m) {
        const unsigned short* qp = qk + (size_t)(b * SEQ + wq0 + m * 16 + l15) * QK_N + h * 64;
        qf[m][0] = *(const bf16x8*)(qp + l4 * 8);
        qf[m][1] = *(const bf16x8*)(qp + 32 + l4 * 8);
    }

    f32x4 o_acc[2][4];
    #pragma unroll
    for (int m = 0; m < 2; ++m)
        #pragma unroll
        for (int n = 0; n < 4; ++n) o_acc[m][n] = (f32x4)0.0f;
    f32x4 l_acc[2] = {(f32x4)0.0f, (f32x4)0.0f};   // partial row sums (ones-MFMA)

    bf16x8 ones;
    #pragma unroll
    for (int j = 0; j < 8; ++j) ones[j] = (short)0x3F80;

    const int srow = l >> 3, g = l & 7;
    const int r0   = w * 16 + srow;           // rows staged by this thread (and +8)
    const int wso  = (g ^ srow) << 3;         // swizzled granule offset (ushorts)
    unsigned short* pw = Ps[w];

    // walking source pointers (hoisted 64-bit address math)
    const unsigned short* kp = qk + (size_t)b * SEQ * QK_N + 1024 + h * 64
                                  + (size_t)r0 * QK_N + g * 8;
    const unsigned short* vp = vtD + (size_t)(h * 64 + r0) * VT_N + b * SEQ + g * 8;

    // prologue: prefetch tile 0 into registers (T14)
    bf16x8 kreg[2], vreg[2];
    kreg[0] = *(const bf16x8*)(kp);
    kreg[1] = *(const bf16x8*)(kp + 8 * QK_N);
    vreg[0] = *(const bf16x8*)(vp);
    vreg[1] = *(const bf16x8*)(vp + 8 * VT_N);
    kp += (size_t)64 * QK_N;
    vp += 64;

    for (int kt = 0; kt < NT; ++kt) {
        __syncthreads();   // previous tile's LDS reads done
        #pragma unroll
        for (int c = 0; c < 2; ++c) {
            *(bf16x8*)(Ks  + (r0 + c * 8) * 64 + wso) = kreg[c];
            *(bf16x8*)(Vts + (r0 + c * 8) * 64 + wso) = vreg[c];
        }
        __syncthreads();   // tile staged

        // issue next tile's global loads; latency hides under compute below
        if (kt + 1 < NT) {
            kreg[0] = *(const bf16x8*)(kp);
            kreg[1] = *(const bf16x8*)(kp + 8 * QK_N);
            vreg[0] = *(const bf16x8*)(vp);
            vreg[1] = *(const bf16x8*)(vp + 8 * VT_N);
            kp += (size_t)64 * QK_N;
            vp += 64;
        }

        // S^T = K Q^T over the wave's 32x32 patch:
        // s_acc[n2][m]: k-row = kt*64 + kh*32 + n2*16 + l4*4 + r2, q-col = wq0 + m*16 + l15
        f32x4 s_acc[2][2];
        #pragma unroll
        for (int n2 = 0; n2 < 2; ++n2)
            #pragma unroll
            for (int m = 0; m < 2; ++m) s_acc[n2][m] = (f32x4)0.0f;
        __builtin_amdgcn_s_setprio(1);
        #pragma unroll
        for (int ks = 0; ks < 2; ++ks) {
            #pragma unroll
            for (int n2 = 0; n2 < 2; ++n2) {
                int row = kh * 32 + n2 * 16 + l15;
                bf16x8 kf = *(const bf16x8*)((const char*)Ks + row * 128 + (((ks * 4 + l4) ^ (row & 7)) << 4));
                #pragma unroll
                for (int m = 0; m < 2; ++m)
                    s_acc[n2][m] = __builtin_amdgcn_mfma_f32_16x16x32_bf16(kf, qf[m][ks], s_acc[n2][m], 0, 0, 0);
            }
        }
        __builtin_amdgcn_s_setprio(0);

        if (causal) {
            int kk0 = kt * 64 + kh * 32;
            #pragma unroll
            for (int n2 = 0; n2 < 2; ++n2)
                #pragma unroll
                for (int m = 0; m < 2; ++m)
                    #pragma unroll
                    for (int r2 = 0; r2 < 4; ++r2) {
                        int krow = kk0 + n2 * 16 + l4 * 4 + r2;
                        int qcol = wq0 + m * 16 + l15;
                        if (krow > qcol) s_acc[n2][m][r2] = -INFINITY;
                    }
        }

        // P = exp2(S) raw; pack pairs (compiler cvt_pk); write b64 into 80B-stride
        // P rows (bank-spread: base bank cycles (prow*20)%32, 2-way max = free)
        #pragma unroll
        for (int m = 0; m < 2; ++m) {
            int prow = m * 16 + l15;
            #pragma unroll
            for (int n2 = 0; n2 < 2; ++n2) {
                float p0 = exp2f(s_acc[n2][m][0]);
                float p1 = exp2f(s_acc[n2][m][1]);
                float p2 = exp2f(s_acc[n2][m][2]);
                float p3 = exp2f(s_acc[n2][m][3]);
                uint2 pk;
                pk.x = pk2c(p0, p1);
                pk.y = pk2c(p2, p3);
                *(uint2*)((char*)pw + prow * 80 + n2 * 32 + l4 * 8) = pk;
            }
        }

        // O += P V over the wave's k-half (single K=32 chunk); l via ones-MFMA
        __builtin_amdgcn_s_setprio(1);
        bf16x8 pf[2];
        #pragma unroll
        for (int m = 0; m < 2; ++m) {
            int prow = m * 16 + l15;
            pf[m] = *(const bf16x8*)((const char*)pw + prow * 80 + l4 * 16);
            l_acc[m] = __builtin_amdgcn_mfma_f32_16x16x32_bf16(pf[m], ones, l_acc[m], 0, 0, 0);
        }
        #pragma unroll
        for (int n = 0; n < 4; ++n) {
            int vrow = n * 16 + l15;
            bf16x8 vf = *(const bf16x8*)((const char*)Vts + vrow * 128 + (((kh * 4 + l4) ^ (vrow & 7)) << 4));
            #pragma unroll
            for (int m = 0; m < 2; ++m)
                o_acc[m][n] = __builtin_amdgcn_mfma_f32_16x16x32_bf16(pf[m], vf, o_acc[m][n], 0, 0, 0);
        }
        __builtin_amdgcn_s_setprio(0);
    }

    // ---- cross-wave merge: (qh, kh=0) += (qh, kh=1); normalize; write --------
    __syncthreads();                           // all tiles' LDS reads done
    float* mq = (float*)(qh ? Vts : Ks);       // 32q x 64d f32 = 8KB per q-half
    float* lb = (float*)&Ps[0][0];             // 64 f32 row sums
    if (kh == 1) {
        #pragma unroll
        for (int m = 0; m < 2; ++m) {
            #pragma unroll
            for (int r2 = 0; r2 < 4; ++r2) {
                int qr = m * 16 + l4 * 4 + r2;
                #pragma unroll
                for (int n = 0; n < 4; ++n)
                    mq[qr * 64 + n * 16 + l15] = o_acc[m][n][r2];
                if (l15 == 0) lb[qh * 32 + qr] = l_acc[m][r2];
            }
        }
    }
    __syncthreads();
    if (kh == 0) {
        #pragma unroll
        for (int m = 0; m < 2; ++m) {
            #pragma unroll
            for (int r2 = 0; r2 < 4; ++r2) {
                int qr = m * 16 + l4 * 4 + r2;
                float lt = l_acc[m][r2] + lb[qh * 32 + qr];
                float inv = 1.0f / lt;
                size_t orow = (size_t)(b * SEQ + wq0 + qr);
                #pragma unroll
                for (int n = 0; n < 4; ++n) {
                    float o = o_acc[m][n][r2] + mq[qr * 64 + n * 16 + l15];
                    attno[orow * HID + h * 64 + n * 16 + l15] = f2b(o * inv);
                }
            }
        }
    }
}

extern "C" void kernel_launch(void* const* d_in, const int* in_sizes, int n_in,
                              void* d_out, int out_size, void* d_ws, size_t ws_size,
                              hipStream_t stream) {
    const float* features = (const float*)d_in[0];
    const float* qkv_w    = (const float*)d_in[1];
    const float* qkv_b    = (const float*)d_in[2];
    const float* out_w    = (const float*)d_in[3];
    const float* out_b    = (const float*)d_in[4];
    const int*   use_mask = (const int*)d_in[5];

    char* ws = (char*)d_ws;
    unsigned short* fbf     = (unsigned short*)(ws);              // 8 MB  features bf16
    unsigned short* wbf     = (unsigned short*)(ws + 8388608);    // 6 MB  qkv_w bf16
    unsigned short* owbf    = (unsigned short*)(ws + 14680064);   // 2 MB  out_w bf16
    unsigned short* qkbf    = (unsigned short*)(ws + 16777216);   // 16 MB Q|K bf16 [4096][2048]
    unsigned short* vtD     = (unsigned short*)(ws + 33554432);   // 8 MB  V^T bf16 [1024][4096]
    unsigned short* attnobf = (unsigned short*)(ws + 41943040);   // 8 MB  attn out bf16

    cvt_all<<<8192, 256, 0, stream>>>(features, fbf, 1048576,
                                      qkv_w, wbf, 786432,
                                      out_w, owbf, 262144);

    // fused QK + V^T projection (768 blocks, one dispatch)
    proj_fused<<<768, 256, 0, stream>>>(fbf, wbf, qkv_b, qkbf, vtD);

    attn_mfma<<<1024, 256, 0, stream>>>(qkbf, vtD, attnobf, use_mask);

    // output projection: [4096,1024] @ [1024,1024]^T + b, 128x64 tiles
    dim3 g3(HID / 64, ROWS / 128);      // (16, 32) = 512 blocks
    gemm_out<<<g3, 256, 0, stream>>>(attnobf, owbf, out_b, (float*)d_out,
                                     ROWS, HID, HID);
}

// Round 15
// 130.495 us; speedup vs baseline: 1.1940x; 1.0843x over previous
//
#include <hip/hip_runtime.h>
#include <hip/hip_bf16.h>
#include <math.h>

#define BATCH 2
#define SEQ   2048
#define HID   1024
#define NHEAD 16
#define ROWS  (BATCH*SEQ)   // 4096
#define QK_N  2048          // Q|K buffer row stride
#define VT_N  (BATCH*SEQ)   // V^T buffer row stride (4096)

// Q pre-scaled by 1/sqrt(64) * log2(e): attention works in exp2 domain.
#define Q_SCALE 0.18033688011112042f

typedef __attribute__((ext_vector_type(8))) short bf16x8;   // 8 bf16 in 4 VGPRs
typedef __attribute__((ext_vector_type(4))) float f32x4;

__device__ __forceinline__ unsigned short f2b(float f) {
    unsigned u = __float_as_uint(f);
    u += 0x7FFF + ((u >> 16) & 1);          // round-to-nearest-even
    return (unsigned short)(u >> 16);
}
// pack two f32 -> u32 of 2 bf16 (lo=a, hi=b) via compiler (emits v_cvt_pk_bf16_f32)
__device__ __forceinline__ unsigned pk2c(float a, float b) {
    __hip_bfloat162 h = __float22bfloat162_rn(float2{a, b});
    union { __hip_bfloat162 h2; unsigned u; } cv; cv.h2 = h;
    return cv.u;
}

// global -> LDS direct copy, 16B per lane; LDS dest is wave-uniform base + lane*16
#define GLOAD_LDS16(gp, lp) \
    __builtin_amdgcn_global_load_lds((const __attribute__((address_space(1))) void*)(gp), \
                                     (__attribute__((address_space(3))) void*)(lp), 16, 0, 0)

// fused f32->bf16 conversion, grid-stride (2048 blocks, G11)
__global__ __launch_bounds__(256)
void cvt_all(const float* __restrict__ a, unsigned short* __restrict__ oa, int na4,
             const float* __restrict__ b, unsigned short* __restrict__ ob, int nb4,
             const float* __restrict__ c, unsigned short* __restrict__ oc, int nc4) {
    const int total = na4 + nb4 + nc4;
    const int stride = gridDim.x * 256;
    for (int i = blockIdx.x * 256 + threadIdx.x; i < total; i += stride) {
        const float* src; unsigned short* dst; int j;
        if (i < na4)            { src = a; dst = oa; j = i; }
        else if (i < na4 + nb4) { src = b; dst = ob; j = i - na4; }
        else                    { src = c; dst = oc; j = i - na4 - nb4; }
        float4 v = reinterpret_cast<const float4*>(src)[j];
        ushort4 o;
        o.x = f2b(v.x); o.y = f2b(v.y); o.z = f2b(v.z); o.w = f2b(v.w);
        reinterpret_cast<ushort4*>(dst)[j] = o;
    }
}

// ---- fused QK + V^T projection, one dispatch (BK=32) -------------------------
// blocks 0..511:   QK: C[s][c] = X[s]·Wqk[c] + b[c], c<1024 scaled; stride QK_N
// blocks 512..767: VT: D[hd][s] = Wv[hd]·X[s] + b[2048+hd]; stride VT_N (coalesced)
__global__ __launch_bounds__(256)
void proj_fused(const unsigned short* __restrict__ fbf,
                const unsigned short* __restrict__ wbf,
                const float* __restrict__ qkv_b,
                unsigned short* __restrict__ qkbf,
                unsigned short* __restrict__ vtD) {
    __shared__ __align__(16) unsigned short As[128 * 32];   // 64B rows, swz(row&3)
    __shared__ __align__(16) unsigned short Bs[128 * 32];
    const int tid = threadIdx.x;
    const int w = tid >> 6, l = tid & 63;
    const int wm = w >> 1, wn = w & 1;
    const int l15 = l & 15, l4 = l >> 4;

    const int bx = blockIdx.x;
    const bool isQK = bx < 512;
    const unsigned short* A;
    const unsigned short* Bm;
    long row0, col0;
    if (isQK) {
        row0 = (long)(bx >> 4) * 128;        // 32 row tiles over 4096 seq rows
        col0 = (long)(bx & 15) * 128;        // 16 col tiles over 2048 qk cols
        A = fbf;  Bm = wbf;
    } else {
        int r = bx - 512;
        row0 = (long)(r >> 5) * 128;         // 8 row tiles over 1024 hd rows
        col0 = (long)(r & 31) * 128;         // 32 col tiles over 4096 seq cols
        A = wbf + (size_t)2048 * 1024;       // W_v
        Bm = fbf;
    }

    f32x4 acc[4][4];
    #pragma unroll
    for (int m = 0; m < 4; ++m)
        #pragma unroll
        for (int n = 0; n < 4; ++n) acc[m][n] = (f32x4)0.0f;

    const int lr   = l >> 2;                 // staging row within 16
    const int slot = (l & 3) ^ (lr & 3);     // pre-swizzled source granule

    for (int k0 = 0; k0 < HID; k0 += 32) {
        __syncthreads();
        #pragma unroll
        for (int c = 0; c < 2; ++c) {
            int r = w * 32 + c * 16 + lr;
            GLOAD_LDS16(A  + (row0 + r) * HID + k0 + slot * 8, As + (w * 32 + c * 16) * 32);
            GLOAD_LDS16(Bm + (col0 + r) * HID + k0 + slot * 8, Bs + (w * 32 + c * 16) * 32);
        }
        __syncthreads();

        bf16x8 af[4], bfr[4];
        #pragma unroll
        for (int m = 0; m < 4; ++m) {
            int row = wm * 64 + m * 16 + l15;
            af[m] = *(const bf16x8*)((const char*)As + row * 64 + ((l4 ^ (row & 3)) << 4));
        }
        #pragma unroll
        for (int n = 0; n < 4; ++n) {
            int row = wn * 64 + n * 16 + l15;
            bfr[n] = *(const bf16x8*)((const char*)Bs + row * 64 + ((l4 ^ (row & 3)) << 4));
        }
        #pragma unroll
        for (int m = 0; m < 4; ++m)
            #pragma unroll
            for (int n = 0; n < 4; ++n)
                acc[m][n] = __builtin_amdgcn_mfma_f32_16x16x32_bf16(af[m], bfr[n], acc[m][n], 0, 0, 0);
    }

    #pragma unroll
    for (int m = 0; m < 4; ++m) {
        #pragma unroll
        for (int n = 0; n < 4; ++n) {
            long ccol = col0 + wn * 64 + n * 16 + l15;
            #pragma unroll
            for (int r2 = 0; r2 < 4; ++r2) {
                long crow = row0 + wm * 64 + m * 16 + l4 * 4 + r2;
                if (isQK) {
                    float v = acc[m][n][r2] + qkv_b[ccol];
                    qkbf[crow * QK_N + ccol] = (ccol < 1024) ? f2b(v * Q_SCALE) : f2b(v);
                } else {
                    float v = acc[m][n][r2] + qkv_b[2048 + crow];
                    vtD[crow * VT_N + ccol] = f2b(v);
                }
            }
        }
    }
}

// ---- out-projection: C[M,N] = A[M,K]*B[N,K]^T + bias, 128x64 tile (2 blk/CU) -
__global__ __launch_bounds__(256)
void gemm_out(const unsigned short* __restrict__ A, const unsigned short* __restrict__ B,
              const float* __restrict__ bias, float* __restrict__ Cout,
              int M, int N, int K) {
    __shared__ __align__(16) unsigned short As[128 * 32];   // 8 KB
    __shared__ __align__(16) unsigned short Bs[64 * 32];    // 4 KB
    const int tid = threadIdx.x;
    const int w = tid >> 6, l = tid & 63;
    const int wm = w >> 1, wn = w & 1;       // wave owns 64 rows x 32 cols
    const int l15 = l & 15, l4 = l >> 4;
    const long row0 = (long)blockIdx.y * 128;
    const long col0 = (long)blockIdx.x * 64;

    f32x4 acc[4][2];
    #pragma unroll
    for (int m = 0; m < 4; ++m)
        #pragma unroll
        for (int n = 0; n < 2; ++n) acc[m][n] = (f32x4)0.0f;

    const int lr   = l >> 2;
    const int slot = (l & 3) ^ (lr & 3);

    for (int k0 = 0; k0 < K; k0 += 32) {
        __syncthreads();
        #pragma unroll
        for (int c = 0; c < 2; ++c) {
            int r = w * 32 + c * 16 + lr;
            GLOAD_LDS16(A + (row0 + r) * K + k0 + slot * 8, As + (w * 32 + c * 16) * 32);
        }
        {   // B tile: 64 rows, one load per thread
            int r = w * 16 + lr;
            GLOAD_LDS16(B + (col0 + r) * K + k0 + slot * 8, Bs + (w * 16) * 32);
        }
        __syncthreads();

        bf16x8 af[4], bfr[2];
        #pragma unroll
        for (int m = 0; m < 4; ++m) {
            int row = wm * 64 + m * 16 + l15;
            af[m] = *(const bf16x8*)((const char*)As + row * 64 + ((l4 ^ (row & 3)) << 4));
        }
        #pragma unroll
        for (int n = 0; n < 2; ++n) {
            int row = wn * 32 + n * 16 + l15;
            bfr[n] = *(const bf16x8*)((const char*)Bs + row * 64 + ((l4 ^ (row & 3)) << 4));
        }
        #pragma unroll
        for (int m = 0; m < 4; ++m)
            #pragma unroll
            for (int n = 0; n < 2; ++n)
                acc[m][n] = __builtin_amdgcn_mfma_f32_16x16x32_bf16(af[m], bfr[n], acc[m][n], 0, 0, 0);
    }

    #pragma unroll
    for (int m = 0; m < 4; ++m) {
        #pragma unroll
        for (int n = 0; n < 2; ++n) {
            long ccol = col0 + wn * 32 + n * 16 + l15;
            float bv = bias[ccol];
            #pragma unroll
            for (int r2 = 0; r2 < 4; ++r2) {
                long crow = row0 + wm * 64 + m * 16 + l4 * 4 + r2;
                Cout[crow * N + ccol] = acc[m][n][r2] + bv;
            }
        }
    }
}

// ---- flash attention, bf16 MFMA, k-split wave specialization -----------------
// Only change vs R13: raw v_exp_f32 via __builtin_amdgcn_exp2f (kills the
// __ocml_exp2_f32 libcall wrapper VALU; hw exp2(-inf)=0 preserves causal path).
__global__ __launch_bounds__(256, 4)
void attn_mfma(const unsigned short* __restrict__ qk, const unsigned short* __restrict__ vtD,
               unsigned short* __restrict__ attno, const int* __restrict__ use_mask) {
    __shared__ __align__(16) unsigned short Ks [64 * 64];   // [token][d], swz(row&7)
    __shared__ __align__(16) unsigned short Vts[64 * 64];   // [d][token], swz(row&7)
    __shared__ __align__(16) unsigned short Ps [4][32 * 40];// per-wave P, 80B rows (bank-spread)
    const int tid = threadIdx.x;
    const int w = tid >> 6, l = tid & 63;
    const int l15 = l & 15, l4 = l >> 4;
    // XCD swizzle: 1024 blocks = 8 XCDs x 128; each XCD owns 4 consecutive bh
    const int bid  = blockIdx.x;
    const int orig = (bid & 7) * 128 + (bid >> 3);
    const int qt = orig & 31, bh = orig >> 5;
    const int b = bh >> 4, h = bh & 15;
    const int q0 = qt * 64;                   // block q-range [q0, q0+64)
    const int qh = w & 1, kh = w >> 1;        // wave's q-half / k-half
    const int wq0 = q0 + qh * 32;             // wave q-range [wq0, wq0+32)
    const int causal = use_mask[0];
    const int NT = causal ? (qt + 1) : (SEQ / 64);

    // Q fragments (B-op of swapped QK^T): col q = wq0 + m*16 + l15, d-slice ks*32+l4*8
    bf16x8 qf[2][2];
    #pragma unroll
    for (int m = 0; m < 2; ++m) {
        const unsigned short* qp = qk + (size_t)(b * SEQ + wq0 + m * 16 + l15) * QK_N + h * 64;
        qf[m][0] = *(const bf16x8*)(qp + l4 * 8);
        qf[m][1] = *(const bf16x8*)(qp + 32 + l4 * 8);
    }

    f32x4 o_acc[2][4];
    #pragma unroll
    for (int m = 0; m < 2; ++m)
        #pragma unroll
        for (int n = 0; n < 4; ++n) o_acc[m][n] = (f32x4)0.0f;
    f32x4 l_acc[2] = {(f32x4)0.0f, (f32x4)0.0f};   // partial row sums (ones-MFMA)

    bf16x8 ones;
    #pragma unroll
    for (int j = 0; j < 8; ++j) ones[j] = (short)0x3F80;

    const int srow = l >> 3, g = l & 7;
    const int r0   = w * 16 + srow;           // rows staged by this thread (and +8)
    const int wso  = (g ^ srow) << 3;         // swizzled granule offset (ushorts)
    unsigned short* pw = Ps[w];

    // walking source pointers (hoisted 64-bit address math)
    const unsigned short* kp = qk + (size_t)b * SEQ * QK_N + 1024 + h * 64
                                  + (size_t)r0 * QK_N + g * 8;
    const unsigned short* vp = vtD + (size_t)(h * 64 + r0) * VT_N + b * SEQ + g * 8;

    // prologue: prefetch tile 0 into registers (T14)
    bf16x8 kreg[2], vreg[2];
    kreg[0] = *(const bf16x8*)(kp);
    kreg[1] = *(const bf16x8*)(kp + 8 * QK_N);
    vreg[0] = *(const bf16x8*)(vp);
    vreg[1] = *(const bf16x8*)(vp + 8 * VT_N);
    kp += (size_t)64 * QK_N;
    vp += 64;

    for (int kt = 0; kt < NT; ++kt) {
        __syncthreads();   // previous tile's LDS reads done
        #pragma unroll
        for (int c = 0; c < 2; ++c) {
            *(bf16x8*)(Ks  + (r0 + c * 8) * 64 + wso) = kreg[c];
            *(bf16x8*)(Vts + (r0 + c * 8) * 64 + wso) = vreg[c];
        }
        __syncthreads();   // tile staged

        // issue next tile's global loads; latency hides under compute below
        if (kt + 1 < NT) {
            kreg[0] = *(const bf16x8*)(kp);
            kreg[1] = *(const bf16x8*)(kp + 8 * QK_N);
            vreg[0] = *(const bf16x8*)(vp);
            vreg[1] = *(const bf16x8*)(vp + 8 * VT_N);
            kp += (size_t)64 * QK_N;
            vp += 64;
        }

        // S^T = K Q^T over the wave's 32x32 patch:
        // s_acc[n2][m]: k-row = kt*64 + kh*32 + n2*16 + l4*4 + r2, q-col = wq0 + m*16 + l15
        f32x4 s_acc[2][2];
        #pragma unroll
        for (int n2 = 0; n2 < 2; ++n2)
            #pragma unroll
            for (int m = 0; m < 2; ++m) s_acc[n2][m] = (f32x4)0.0f;
        __builtin_amdgcn_s_setprio(1);
        #pragma unroll
        for (int ks = 0; ks < 2; ++ks) {
            #pragma unroll
            for (int n2 = 0; n2 < 2; ++n2) {
                int row = kh * 32 + n2 * 16 + l15;
                bf16x8 kf = *(const bf16x8*)((const char*)Ks + row * 128 + (((ks * 4 + l4) ^ (row & 7)) << 4));
                #pragma unroll
                for (int m = 0; m < 2; ++m)
                    s_acc[n2][m] = __builtin_amdgcn_mfma_f32_16x16x32_bf16(kf, qf[m][ks], s_acc[n2][m], 0, 0, 0);
            }
        }
        __builtin_amdgcn_s_setprio(0);

        if (causal) {
            int kk0 = kt * 64 + kh * 32;
            #pragma unroll
            for (int n2 = 0; n2 < 2; ++n2)
                #pragma unroll
                for (int m = 0; m < 2; ++m)
                    #pragma unroll
                    for (int r2 = 0; r2 < 4; ++r2) {
                        int krow = kk0 + n2 * 16 + l4 * 4 + r2;
                        int qcol = wq0 + m * 16 + l15;
                        if (krow > qcol) s_acc[n2][m][r2] = -INFINITY;
                    }
        }

        // P = exp2(S) raw (single v_exp_f32 each); pack pairs; write b64 into
        // 80B-stride P rows (bank-spread)
        #pragma unroll
        for (int m = 0; m < 2; ++m) {
            int prow = m * 16 + l15;
            #pragma unroll
            for (int n2 = 0; n2 < 2; ++n2) {
                float p0 = __builtin_amdgcn_exp2f(s_acc[n2][m][0]);
                float p1 = __builtin_amdgcn_exp2f(s_acc[n2][m][1]);
                float p2 = __builtin_amdgcn_exp2f(s_acc[n2][m][2]);
                float p3 = __builtin_amdgcn_exp2f(s_acc[n2][m][3]);
                uint2 pk;
                pk.x = pk2c(p0, p1);
                pk.y = pk2c(p2, p3);
                *(uint2*)((char*)pw + prow * 80 + n2 * 32 + l4 * 8) = pk;
            }
        }

        // O += P V over the wave's k-half (single K=32 chunk); l via ones-MFMA
        __builtin_amdgcn_s_setprio(1);
        bf16x8 pf[2];
        #pragma unroll
        for (int m = 0; m < 2; ++m) {
            int prow = m * 16 + l15;
            pf[m] = *(const bf16x8*)((const char*)pw + prow * 80 + l4 * 16);
            l_acc[m] = __builtin_amdgcn_mfma_f32_16x16x32_bf16(pf[m], ones, l_acc[m], 0, 0, 0);
        }
        #pragma unroll
        for (int n = 0; n < 4; ++n) {
            int vrow = n * 16 + l15;
            bf16x8 vf = *(const bf16x8*)((const char*)Vts + vrow * 128 + (((kh * 4 + l4) ^ (vrow & 7)) << 4));
            #pragma unroll
            for (int m = 0; m < 2; ++m)
                o_acc[m][n] = __builtin_amdgcn_mfma_f32_16x16x32_bf16(pf[m], vf, o_acc[m][n], 0, 0, 0);
        }
        __builtin_amdgcn_s_setprio(0);
    }

    // ---- cross-wave merge: (qh, kh=0) += (qh, kh=1); normalize; write --------
    __syncthreads();                           // all tiles' LDS reads done
    float* mq = (float*)(qh ? Vts : Ks);       // 32q x 64d f32 = 8KB per q-half
    float* lb = (float*)&Ps[0][0];             // 64 f32 row sums
    if (kh == 1) {
        #pragma unroll
        for (int m = 0; m < 2; ++m) {
            #pragma unroll
            for (int r2 = 0; r2 < 4; ++r2) {
                int qr = m * 16 + l4 * 4 + r2;
                #pragma unroll
                for (int n = 0; n < 4; ++n)
                    mq[qr * 64 + n * 16 + l15] = o_acc[m][n][r2];
                if (l15 == 0) lb[qh * 32 + qr] = l_acc[m][r2];
            }
        }
    }
    __syncthreads();
    if (kh == 0) {
        #pragma unroll
        for (int m = 0; m < 2; ++m) {
            #pragma unroll
            for (int r2 = 0; r2 < 4; ++r2) {
                int qr = m * 16 + l4 * 4 + r2;
                float lt = l_acc[m][r2] + lb[qh * 32 + qr];
                float inv = 1.0f / lt;
                size_t orow = (size_t)(b * SEQ + wq0 + qr);
                #pragma unroll
                for (int n = 0; n < 4; ++n) {
                    float o = o_acc[m][n][r2] + mq[qr * 64 + n * 16 + l15];
                    attno[orow * HID + h * 64 + n * 16 + l15] = f2b(o * inv);
                }
            }
        }
    }
}

extern "C" void kernel_launch(void* const* d_in, const int* in_sizes, int n_in,
                              void* d_out, int out_size, void* d_ws, size_t ws_size,
                              hipStream_t stream) {
    const float* features = (const float*)d_in[0];
    const float* qkv_w    = (const float*)d_in[1];
    const float* qkv_b    = (const float*)d_in[2];
    const float* out_w    = (const float*)d_in[3];
    const float* out_b    = (const float*)d_in[4];
    const int*   use_mask = (const int*)d_in[5];

    char* ws = (char*)d_ws;
    unsigned short* fbf     = (unsigned short*)(ws);              // 8 MB  features bf16
    unsigned short* wbf     = (unsigned short*)(ws + 8388608);    // 6 MB  qkv_w bf16
    unsigned short* owbf    = (unsigned short*)(ws + 14680064);   // 2 MB  out_w bf16
    unsigned short* qkbf    = (unsigned short*)(ws + 16777216);   // 16 MB Q|K bf16 [4096][2048]
    unsigned short* vtD     = (unsigned short*)(ws + 33554432);   // 8 MB  V^T bf16 [1024][4096]
    unsigned short* attnobf = (unsigned short*)(ws + 41943040);   // 8 MB  attn out bf16

    cvt_all<<<2048, 256, 0, stream>>>(features, fbf, 1048576,
                                      qkv_w, wbf, 786432,
                                      out_w, owbf, 262144);

    // fused QK + V^T projection (768 blocks, one dispatch)
    proj_fused<<<768, 256, 0, stream>>>(fbf, wbf, qkv_b, qkbf, vtD);

    attn_mfma<<<1024, 256, 0, stream>>>(qkbf, vtD, attnobf, use_mask);

    // output projection: [4096,1024] @ [1024,1024]^T + b, 128x64 tiles
    dim3 g3(HID / 64, ROWS / 128);      // (16, 32) = 512 blocks
    gemm_out<<<g3, 256, 0, stream>>>(attnobf, owbf, out_b, (float*)d_out,
                                     ROWS, HID, HID);
}